// Round 10
// baseline (376.368 us; speedup 1.0000x reference)
//
#include <hip/hip_runtime.h>
#include <hip/hip_fp16.h>

// IGCN forward, round 10: round-9 base (fp16 state, u16 local cols) with
//  (a) SpMM dispatches re-split by bipartite half so each kernel gathers from
//      ONE source buffer (5-8 MB) -> near-L2-resident per XCD instead of LLC.
//  (b) count/scatter ranges 8 -> 4: halves the pair-stream re-read.
//  - ONE CSR serves feat-SpMM (+bias, degF=degA+1) and all adj-SpMMs.
//  - Cols stored LOCAL to the opposite half (u16).
//  - Scaled state y~ = rsD[row]*y[row] in fp16; adj inner loop is a pure
//    gather-sum; gathered rows un-scale by sqrt(deg).
//  - SpMM: wave = 8 edge-slots x 8 dim-lanes, 16B H8 per lane, unroll 2.

constexpr int kNU = 60000;
constexpr int kNI = 40000;
constexpr int kN  = 100000;
constexpr int kB  = 4096;
constexpr int kNRange = 4, kRangeSz = 25000;   // 4 * 25000 = 100000
constexpr int kNChunk = 256;

struct alignas(16) H8 { __half2 h[4]; };   // 8 halfs = 16B
struct alignas(8)  H4 { __half2 lo, hi; }; // 4 halfs = 8B

// ---------------- CSR build (ranged, u16 cols) ------------------------------
__global__ void count_deg_ranged(const int4* __restrict__ u4, const int4* __restrict__ i4,
                                 int nV, int* __restrict__ deg) {
  int range = blockIdx.x & (kNRange - 1);
  int chunk = blockIdx.x >> 2;
  int lo = range * kRangeSz, hi = lo + kRangeSz;
  int chunkLen = (nV + kNChunk - 1) / kNChunk;
  int p0 = chunk * chunkLen, p1 = min(nV, p0 + chunkLen);
  for (int p = p0 + (int)threadIdx.x; p < p1; p += 256) {
    int4 uu = u4[p], ii = i4[p];
    if (uu.x >= lo && uu.x < hi) atomicAdd(&deg[uu.x], 1);
    if (uu.y >= lo && uu.y < hi) atomicAdd(&deg[uu.y], 1);
    if (uu.z >= lo && uu.z < hi) atomicAdd(&deg[uu.z], 1);
    if (uu.w >= lo && uu.w < hi) atomicAdd(&deg[uu.w], 1);
    if (ii.x >= lo && ii.x < hi) atomicAdd(&deg[ii.x], 1);
    if (ii.y >= lo && ii.y < hi) atomicAdd(&deg[ii.y], 1);
    if (ii.z >= lo && ii.z < hi) atomicAdd(&deg[ii.z], 1);
    if (ii.w >= lo && ii.w < hi) atomicAdd(&deg[ii.w], 1);
  }
}

__global__ void scatter_ranged(const int4* __restrict__ u4, const int4* __restrict__ i4,
                               int nV, int* __restrict__ cur,
                               unsigned short* __restrict__ colsOut) {
  int range = blockIdx.x & (kNRange - 1);
  int chunk = blockIdx.x >> 2;
  int lo = range * kRangeSz, hi = lo + kRangeSz;
  int chunkLen = (nV + kNChunk - 1) / kNChunk;
  int p0 = chunk * chunkLen, p1 = min(nV, p0 + chunkLen);
  for (int p = p0 + (int)threadIdx.x; p < p1; p += 256) {
    int4 uu = u4[p], ii = i4[p];
    // user rows store item-LOCAL idx; item rows store user idx
    if (uu.x >= lo && uu.x < hi) colsOut[atomicAdd(&cur[uu.x], 1)] = (unsigned short)(ii.x - kNU);
    if (ii.x >= lo && ii.x < hi) colsOut[atomicAdd(&cur[ii.x], 1)] = (unsigned short)uu.x;
    if (uu.y >= lo && uu.y < hi) colsOut[atomicAdd(&cur[uu.y], 1)] = (unsigned short)(ii.y - kNU);
    if (ii.y >= lo && ii.y < hi) colsOut[atomicAdd(&cur[ii.y], 1)] = (unsigned short)uu.y;
    if (uu.z >= lo && uu.z < hi) colsOut[atomicAdd(&cur[uu.z], 1)] = (unsigned short)(ii.z - kNU);
    if (ii.z >= lo && ii.z < hi) colsOut[atomicAdd(&cur[ii.z], 1)] = (unsigned short)uu.z;
    if (uu.w >= lo && uu.w < hi) colsOut[atomicAdd(&cur[uu.w], 1)] = (unsigned short)(ii.w - kNU);
    if (ii.w >= lo && ii.w < hi) colsOut[atomicAdd(&cur[ii.w], 1)] = (unsigned short)uu.w;
  }
}

// ---------------- scan ----------------
constexpr int SCAN_T = 256, SCAN_E = 8, SCAN_CH = SCAN_T * SCAN_E;  // 2048

__global__ void scan_p1(const int* __restrict__ in, int n, int* __restrict__ bsum) {
  __shared__ int lds[SCAN_T];
  int t = threadIdx.x;
  int base = blockIdx.x * SCAN_CH + t * SCAN_E;
  int s = 0;
  #pragma unroll
  for (int k = 0; k < SCAN_E; ++k) { int i = base + k; if (i < n) s += in[i]; }
  lds[t] = s; __syncthreads();
  for (int off = SCAN_T / 2; off; off >>= 1) {
    if (t < off) lds[t] += lds[t + off];
    __syncthreads();
  }
  if (t == 0) bsum[blockIdx.x] = lds[0];
}

__global__ void scan_p2(int* bsum, int nb) {
  if (threadIdx.x == 0 && blockIdx.x == 0) {
    int run = 0;
    for (int i = 0; i < nb; ++i) { int v = bsum[i]; bsum[i] = run; run += v; }
  }
}

__global__ void scan_p3(const int* __restrict__ in, int n, int ntot,
                        const int* __restrict__ bsum,
                        int* __restrict__ out, int* __restrict__ cur,
                        float* __restrict__ rsDg) {
  __shared__ int lds[SCAN_T];
  int t = threadIdx.x;
  int base = blockIdx.x * SCAN_CH + t * SCAN_E;
  int v[SCAN_E]; int s = 0;
  #pragma unroll
  for (int k = 0; k < SCAN_E; ++k) { int i = base + k; v[k] = (i < n) ? in[i] : 0; s += v[k]; }
  lds[t] = s; __syncthreads();
  for (int off = 1; off < SCAN_T; off <<= 1) {
    int x = (t >= off) ? lds[t - off] : 0;
    __syncthreads();
    lds[t] += x;
    __syncthreads();
  }
  int pre = lds[t] - s + bsum[blockIdx.x];
  #pragma unroll
  for (int k = 0; k < SCAN_E; ++k) {
    int i = base + k;
    if (i < n) {
      out[i] = pre; cur[i] = pre; pre += v[k];
      rsDg[i] = v[k] > 0 ? rsqrtf((float)v[k]) : 1.f;   // fused make_rsd
    }
  }
  if (blockIdx.x == 0 && t == 0) out[n] = ntot;
}

// ---------------- emb fp32 -> fp16 ------------------------------------------
__global__ void emb_to_h(const float4* __restrict__ in, H4* __restrict__ outp, int n) {
  int i = blockIdx.x * 256 + threadIdx.x;
  if (i < n) {
    float4 v = in[i];
    float2 lo = {v.x, v.y}, hi = {v.z, v.w};
    H4 o; o.lo = __float22half2_rn(lo); o.hi = __float22half2_rn(hi);
    outp[i] = o;
  }
}

// ---------------- feat SpMM, one half: fp16 emb gather -> fp16 y~0 ----------
// wave = 8 edge-slots x 8 dim-lanes (16B H8), unroll 2. One gather source.
__global__ void spmm_feat_half(const int* __restrict__ rs, const unsigned short* __restrict__ cols,
                               const H8* __restrict__ emb16, const float* __restrict__ rsDg,
                               H8* __restrict__ dstHalf, int row0, int nrows,
                               int embBase, int biasIdx) {
  int r = blockIdx.x * 4 + (threadIdx.x >> 6);
  if (r >= nrows) return;
  int row = row0 + r;
  int lane = threadIdx.x & 63, g = lane >> 3, q = lane & 7;
  int s = rs[row], e = rs[row + 1];
  float a[8];
  #pragma unroll
  for (int k = 0; k < 8; ++k) a[k] = 0.f;
  int j = s + g;
  for (; j + 8 < e; j += 16) {
    int c0 = cols[j], c1 = cols[j + 8];
    H8 v0 = emb16[(long)(embBase + c0) * 8 + q];
    H8 v1 = emb16[(long)(embBase + c1) * 8 + q];
    #pragma unroll
    for (int k = 0; k < 4; ++k) {
      float2 f0 = __half22float2(v0.h[k]);
      float2 f1 = __half22float2(v1.h[k]);
      a[2 * k]     += f0.x + f1.x;
      a[2 * k + 1] += f0.y + f1.y;
    }
  }
  if (j < e) {
    int c = cols[j];
    H8 v = emb16[(long)(embBase + c) * 8 + q];
    #pragma unroll
    for (int k = 0; k < 4; ++k) {
      float2 f = __half22float2(v.h[k]);
      a[2 * k] += f.x; a[2 * k + 1] += f.y;
    }
  }
  #pragma unroll
  for (int m = 8; m <= 32; m <<= 1) {
    #pragma unroll
    for (int k = 0; k < 8; ++k) a[k] += __shfl_xor(a[k], m, 64);
  }
  if (g == 0) {
    H8 bv = emb16[(long)biasIdx * 8 + q];
    float sc = rsDg[row] / (float)(e - s + 1);
    H8 o;
    #pragma unroll
    for (int k = 0; k < 4; ++k) {
      float2 bf = __half22float2(bv.h[k]);
      float2 f = {(a[2 * k] + bf.x) * sc, (a[2 * k + 1] + bf.y) * sc};
      o.h[k] = __float22half2_rn(f);
    }
    dstHalf[(long)r * 8 + q] = o;
  }
}

// ---------------- adj SpMM, one half: fp16 gather-sum -> fp16 ---------------
__global__ void spmm_adj_half(const int* __restrict__ rs, const unsigned short* __restrict__ cols,
                              const float* __restrict__ rsDg,
                              const H8* __restrict__ src, H8* __restrict__ dst,
                              int row0, int nrows) {
  int r = blockIdx.x * 4 + (threadIdx.x >> 6);
  if (r >= nrows) return;
  int row = row0 + r;
  int lane = threadIdx.x & 63, g = lane >> 3, q = lane & 7;
  int s = rs[row], e = rs[row + 1];
  float a[8];
  #pragma unroll
  for (int k = 0; k < 8; ++k) a[k] = 0.f;
  int j = s + g;
  for (; j + 8 < e; j += 16) {
    int c0 = cols[j], c1 = cols[j + 8];
    H8 v0 = src[(long)c0 * 8 + q];
    H8 v1 = src[(long)c1 * 8 + q];
    #pragma unroll
    for (int k = 0; k < 4; ++k) {
      float2 f0 = __half22float2(v0.h[k]);
      float2 f1 = __half22float2(v1.h[k]);
      a[2 * k]     += f0.x + f1.x;
      a[2 * k + 1] += f0.y + f1.y;
    }
  }
  if (j < e) {
    int c = cols[j];
    H8 v = src[(long)c * 8 + q];
    #pragma unroll
    for (int k = 0; k < 4; ++k) {
      float2 f = __half22float2(v.h[k]);
      a[2 * k] += f.x; a[2 * k + 1] += f.y;
    }
  }
  #pragma unroll
  for (int m = 8; m <= 32; m <<= 1) {
    #pragma unroll
    for (int k = 0; k < 8; ++k) a[k] += __shfl_xor(a[k], m, 64);
  }
  if (g == 0) {
    float w = rsDg[row]; w = w * w;   // = 1/deg (deg>0); empty row -> 0 sum
    H8 o;
    #pragma unroll
    for (int k = 0; k < 4; ++k) {
      float2 f = {a[2 * k] * w, a[2 * k + 1] * w};
      o.h[k] = __float22half2_rn(f);
    }
    dst[(long)r * 8 + q] = o;
  }
}

// ---------------- gathered-row accumulation (un-scale by sqrt(deg)) ---------
__global__ void acc_gather_h(const H8* __restrict__ hU, const H8* __restrict__ hI,
                             const int* __restrict__ deg,
                             const int* __restrict__ users, const int* __restrict__ pos,
                             const int* __restrict__ neg, float4* __restrict__ out, int add) {
  int gI = blockIdx.x * blockDim.x + threadIdx.x;
  if (gI >= 3 * kB * 8) return;
  int slot = gI >> 3, q = gI & 7;
  int which = slot >> 12, b = slot & (kB - 1);
  int node = which == 0 ? users[b] : (which == 1 ? pos[b] + kNU : neg[b] + kNU);
  H8 v = (node < kNU) ? hU[(long)node * 8 + q] : hI[(long)(node - kNU) * 8 + q];
  float sq = sqrtf((float)max(deg[node], 1));
  float2 f0 = __half22float2(v.h[0]), f1 = __half22float2(v.h[1]);
  float2 f2 = __half22float2(v.h[2]), f3 = __half22float2(v.h[3]);
  float4 r0 = {f0.x * sq, f0.y * sq, f1.x * sq, f1.y * sq};
  float4 r1 = {f2.x * sq, f2.y * sq, f3.x * sq, f3.y * sq};
  long o0 = (long)slot * 16 + q * 2;
  if (add) {
    float4 a0 = out[o0], a1 = out[o0 + 1];
    r0.x += a0.x; r0.y += a0.y; r0.z += a0.z; r0.w += a0.w;
    r1.x += a1.x; r1.y += a1.y; r1.z += a1.z; r1.w += a1.w;
  }
  out[o0] = r0; out[o0 + 1] = r1;
}

// ---------------- layer 3 restricted + /4 + per-row L2 ----------------------
__global__ void layer3_fin(const int* __restrict__ rs, const unsigned short* __restrict__ cols,
                           const float* __restrict__ rsDg,
                           const H8* __restrict__ hU, const H8* __restrict__ hI,
                           const int* __restrict__ users, const int* __restrict__ pos,
                           const int* __restrict__ neg,
                           float4* __restrict__ out, float* __restrict__ l2part) {
  int slot = blockIdx.x * 4 + (threadIdx.x >> 6);
  if (slot >= 3 * kB) return;
  int lane = threadIdx.x & 63, g = lane >> 3, q = lane & 7;
  int which = slot >> 12, b = slot & (kB - 1);
  int node = which == 0 ? users[b] : (which == 1 ? pos[b] + kNU : neg[b] + kNU);
  const H8* src = (node < kNU) ? hI : hU;
  int s = rs[node], e = rs[node + 1];
  float a[8];
  #pragma unroll
  for (int k = 0; k < 8; ++k) a[k] = 0.f;
  int j = s + g;
  for (; j + 8 < e; j += 16) {
    int c0 = cols[j], c1 = cols[j + 8];
    H8 v0 = src[(long)c0 * 8 + q];
    H8 v1 = src[(long)c1 * 8 + q];
    #pragma unroll
    for (int k = 0; k < 4; ++k) {
      float2 f0 = __half22float2(v0.h[k]);
      float2 f1 = __half22float2(v1.h[k]);
      a[2 * k]     += f0.x + f1.x;
      a[2 * k + 1] += f0.y + f1.y;
    }
  }
  if (j < e) {
    int c = cols[j];
    H8 v = src[(long)c * 8 + q];
    #pragma unroll
    for (int k = 0; k < 4; ++k) {
      float2 f = __half22float2(v.h[k]);
      a[2 * k] += f.x; a[2 * k + 1] += f.y;
    }
  }
  #pragma unroll
  for (int m = 8; m <= 32; m <<= 1) {
    #pragma unroll
    for (int k = 0; k < 8; ++k) a[k] += __shfl_xor(a[k], m, 64);
  }
  float t = 0.f;
  if (g == 0) {
    float sr = rsDg[node];   // y3 = rsDg * sum(in~)
    long o0 = (long)slot * 16 + q * 2;
    float4 a0 = out[o0], a1 = out[o0 + 1];
    float4 r0 = {(a0.x + a[0] * sr) * 0.25f, (a0.y + a[1] * sr) * 0.25f,
                 (a0.z + a[2] * sr) * 0.25f, (a0.w + a[3] * sr) * 0.25f};
    float4 r1 = {(a1.x + a[4] * sr) * 0.25f, (a1.y + a[5] * sr) * 0.25f,
                 (a1.z + a[6] * sr) * 0.25f, (a1.w + a[7] * sr) * 0.25f};
    out[o0] = r0; out[o0 + 1] = r1;
    t = r0.x * r0.x + r0.y * r0.y + r0.z * r0.z + r0.w * r0.w
      + r1.x * r1.x + r1.y * r1.y + r1.z * r1.z + r1.w * r1.w;
  }
  #pragma unroll
  for (int m = 1; m <= 4; m <<= 1) t += __shfl_xor(t, m, 64);
  if (lane == 0) l2part[slot] = t;
}

__global__ void l2_final(const float* __restrict__ l2part, float* __restrict__ outl2) {
  int b = blockIdx.x * blockDim.x + threadIdx.x;
  if (b < kB) outl2[b] = l2part[b] + l2part[kB + b] + l2part[2 * kB + b];
}

extern "C" void kernel_launch(void* const* d_in, const int* in_sizes, int n_in,
                              void* d_out, int out_size, void* d_ws, size_t ws_size,
                              hipStream_t stream) {
  const float* emb  = (const float*)d_in[0];
  const int*   arow = (const int*)d_in[3];
  const int*   users= (const int*)d_in[5];
  const int*   pos  = (const int*)d_in[6];
  const int*   neg  = (const int*)d_in[7];
  const int neA = in_sizes[3];              // 2,000,000
  const int nP  = neA / 2;                  // 1,000,000 pairs
  const int nV  = nP / 4;
  const int4* u4 = (const int4*)arow;
  const int4* i4 = (const int4*)(arow + nP);

  char* ws = (char*)d_ws;
  int*            degA   = (int*)(ws + 0);            // 400,000
  int*            rsArr  = (int*)(ws + 400000);       // 400,004 (pad to 400128)
  int*            cur    = (int*)(ws + 800128);       // 400,000
  float*          rsDg   = (float*)(ws + 1200128);    // 400,000
  float*          l2part = (float*)(ws + 1600128);    // 49,152
  int*            bsum   = (int*)(ws + 1649280);      // 1,024
  unsigned short* colA   = (unsigned short*)(ws + 1650304);  // 4,000,000
  __half*         emb16  = (__half*)(ws + 5650304);   // 12,800,256 (pad to 12800320)
  __half*         hU0    = (__half*)(ws + 18450624);  // 7,680,000
  __half*         hU1    = (__half*)(ws + 26130624);  // 7,680,000
  __half*         hI0    = (__half*)(ws + 33810624);  // 5,120,000
  __half*         hI1    = (__half*)(ws + 38930624);  // 5,120,000 -> end 44,050,624

  float* out = (float*)d_out;
  const int NB = (kN + SCAN_CH - 1) / SCAN_CH;  // 49

  hipMemsetAsync(degA, 0, 400000, stream);
  count_deg_ranged<<<kNRange * kNChunk, 256, 0, stream>>>(u4, i4, nV, degA);
  scan_p1<<<NB, SCAN_T, 0, stream>>>(degA, kN, bsum);
  scan_p2<<<1, 64, 0, stream>>>(bsum, NB);
  scan_p3<<<NB, SCAN_T, 0, stream>>>(degA, kN, neA, bsum, rsArr, cur, rsDg);
  const int nE16 = 100002 * 16;   // float4 elements in emb
  emb_to_h<<<(nE16 + 255) / 256, 256, 0, stream>>>((const float4*)emb, (H4*)emb16, nE16);
  scatter_ranged<<<kNRange * kNChunk, 256, 0, stream>>>(u4, i4, nV, cur, colA);

  const int GU = (kNU + 3) / 4, GI = (kNI + 3) / 4;
  const H8* E16 = (const H8*)emb16;

  // feature SpMM (split halves) -> fp16 scaled state y~0
  spmm_feat_half<<<GU, 256, 0, stream>>>(rsArr, colA, E16, rsDg, (H8*)hU0, 0, kNU,
                                         kNU, 100000);
  spmm_feat_half<<<GI, 256, 0, stream>>>(rsArr, colA, E16, rsDg, (H8*)hI0, kNU, kNI,
                                         0, 100001);
  acc_gather_h<<<(3 * kB * 8 + 255) / 256, 256, 0, stream>>>((const H8*)hU0, (const H8*)hI0,
      degA, users, pos, neg, (float4*)out, 0);

  // layer 1: (hU0,hI0) -> (hU1,hI1)   [items read hU0; users read hI0]
  spmm_adj_half<<<GI, 256, 0, stream>>>(rsArr, colA, rsDg, (const H8*)hU0, (H8*)hI1,
                                        kNU, kNI);
  spmm_adj_half<<<GU, 256, 0, stream>>>(rsArr, colA, rsDg, (const H8*)hI0, (H8*)hU1,
                                        0, kNU);
  acc_gather_h<<<(3 * kB * 8 + 255) / 256, 256, 0, stream>>>((const H8*)hU1, (const H8*)hI1,
      degA, users, pos, neg, (float4*)out, 1);

  // layer 2: (hU1,hI1) -> (hU0,hI0)
  spmm_adj_half<<<GI, 256, 0, stream>>>(rsArr, colA, rsDg, (const H8*)hU1, (H8*)hI0,
                                        kNU, kNI);
  spmm_adj_half<<<GU, 256, 0, stream>>>(rsArr, colA, rsDg, (const H8*)hI1, (H8*)hU0,
                                        0, kNU);
  acc_gather_h<<<(3 * kB * 8 + 255) / 256, 256, 0, stream>>>((const H8*)hU0, (const H8*)hI0,
      degA, users, pos, neg, (float4*)out, 1);

  // layer 3 restricted + epilogue (reads layer-2 state)
  layer3_fin<<<(3 * kB + 3) / 4, 256, 0, stream>>>(rsArr, colA, rsDg, (const H8*)hU0,
                                                   (const H8*)hI0, users, pos, neg,
                                                   (float4*)out, l2part);
  l2_final<<<(kB + 255) / 256, 256, 0, stream>>>(l2part, out + 3 * kB * 64);
}

// Round 11
// 227.318 us; speedup vs baseline: 1.6557x; 1.6557x over previous
//
#include <hip/hip_runtime.h>
#include <hip/hip_fp16.h>

// IGCN forward, round 11: ATOMIC-FREE CSR build via (range x chunk) histogram.
//  k1: LDS histogram per (range,chunk) block -> hist[r][c][localRow] (coalesced).
//  k2: row-sum hist -> deg, rsDg.   scan -> rowStart.
//  k6: in-place prefix over chunks + rowStart -> per-(row,chunk) base.
//  k7: re-stream pairs, LDS-atomic rank against the base plane, plain u16 col
//      stores. Zero device-scope atomics in the whole build.
//  hist (25.6MB) aliases the fp16 state buffers (dead until feat SpMM).
//  SpMM side = round-9 merged kernels (fp16 scaled state, u16 local cols).

constexpr int kNU = 60000;
constexpr int kNI = 40000;
constexpr int kN  = 100000;
constexpr int kB  = 4096;
constexpr int NR  = 8,  RSZ = 12500;   // row ranges
constexpr int NC  = 64;                // chunks per range

struct alignas(16) H8 { __half2 h[4]; };   // 8 halfs = 16B
struct alignas(8)  H4 { __half2 lo, hi; }; // 4 halfs = 8B

// ---------------- k1: LDS histogram ----------------------------------------
__global__ void hist_k(const int4* __restrict__ u4, const int4* __restrict__ i4,
                       int nV, int* __restrict__ hist) {
  int r = blockIdx.x & (NR - 1), c = blockIdx.x >> 3;
  int lo = r * RSZ;
  __shared__ int h[RSZ];
  for (int i = threadIdx.x; i < RSZ; i += 256) h[i] = 0;
  __syncthreads();
  int cl = (nV + NC - 1) / NC;
  int p0 = c * cl, p1 = min(nV, p0 + cl);
  for (int p = p0 + (int)threadIdx.x; p < p1; p += 256) {
    int4 uu = u4[p], ii = i4[p];
    int a;
    a = uu.x - lo; if ((unsigned)a < (unsigned)RSZ) atomicAdd(&h[a], 1);
    a = ii.x - lo; if ((unsigned)a < (unsigned)RSZ) atomicAdd(&h[a], 1);
    a = uu.y - lo; if ((unsigned)a < (unsigned)RSZ) atomicAdd(&h[a], 1);
    a = ii.y - lo; if ((unsigned)a < (unsigned)RSZ) atomicAdd(&h[a], 1);
    a = uu.z - lo; if ((unsigned)a < (unsigned)RSZ) atomicAdd(&h[a], 1);
    a = ii.z - lo; if ((unsigned)a < (unsigned)RSZ) atomicAdd(&h[a], 1);
    a = uu.w - lo; if ((unsigned)a < (unsigned)RSZ) atomicAdd(&h[a], 1);
    a = ii.w - lo; if ((unsigned)a < (unsigned)RSZ) atomicAdd(&h[a], 1);
  }
  __syncthreads();
  int* dst = hist + (long)(r * NC + c) * RSZ;
  for (int i = threadIdx.x; i < RSZ; i += 256) dst[i] = h[i];
}

// ---------------- k2: deg = row-sum of hist; rsDg ---------------------------
__global__ void degsum_k(const int* __restrict__ hist, int* __restrict__ deg,
                         float* __restrict__ rsDg) {
  int row = blockIdx.x * 256 + threadIdx.x;
  if (row >= kN) return;
  int r = row / RSZ, local = row - r * RSZ;
  const int* base = hist + (long)r * NC * RSZ + local;
  int s = 0;
  for (int c = 0; c < NC; ++c) s += base[(long)c * RSZ];
  deg[row] = s;
  rsDg[row] = s > 0 ? rsqrtf((float)s) : 1.f;
}

// ---------------- scan (rowStart from deg) ----------------------------------
constexpr int SCAN_T = 256, SCAN_E = 8, SCAN_CH = SCAN_T * SCAN_E;  // 2048

__global__ void scan_p1(const int* __restrict__ in, int n, int* __restrict__ bsum) {
  __shared__ int lds[SCAN_T];
  int t = threadIdx.x;
  int base = blockIdx.x * SCAN_CH + t * SCAN_E;
  int s = 0;
  #pragma unroll
  for (int k = 0; k < SCAN_E; ++k) { int i = base + k; if (i < n) s += in[i]; }
  lds[t] = s; __syncthreads();
  for (int off = SCAN_T / 2; off; off >>= 1) {
    if (t < off) lds[t] += lds[t + off];
    __syncthreads();
  }
  if (t == 0) bsum[blockIdx.x] = lds[0];
}

__global__ void scan_p2(int* bsum, int nb) {
  if (threadIdx.x == 0 && blockIdx.x == 0) {
    int run = 0;
    for (int i = 0; i < nb; ++i) { int v = bsum[i]; bsum[i] = run; run += v; }
  }
}

__global__ void scan_p3(const int* __restrict__ in, int n, int ntot,
                        const int* __restrict__ bsum, int* __restrict__ out) {
  __shared__ int lds[SCAN_T];
  int t = threadIdx.x;
  int base = blockIdx.x * SCAN_CH + t * SCAN_E;
  int v[SCAN_E]; int s = 0;
  #pragma unroll
  for (int k = 0; k < SCAN_E; ++k) { int i = base + k; v[k] = (i < n) ? in[i] : 0; s += v[k]; }
  lds[t] = s; __syncthreads();
  for (int off = 1; off < SCAN_T; off <<= 1) {
    int x = (t >= off) ? lds[t - off] : 0;
    __syncthreads();
    lds[t] += x;
    __syncthreads();
  }
  int pre = lds[t] - s + bsum[blockIdx.x];
  #pragma unroll
  for (int k = 0; k < SCAN_E; ++k) {
    int i = base + k;
    if (i < n) { out[i] = pre; pre += v[k]; }
  }
  if (blockIdx.x == 0 && t == 0) out[n] = ntot;
}

// ---------------- k6: expand hist -> per-(row,chunk) base (in place) --------
__global__ void expand_k(int* __restrict__ hist, const int* __restrict__ rowStart) {
  int row = blockIdx.x * 256 + threadIdx.x;
  if (row >= kN) return;
  int r = row / RSZ, local = row - r * RSZ;
  int* base = hist + (long)r * NC * RSZ + local;
  int run = rowStart[row];
  for (int c = 0; c < NC; ++c) {
    long idx = (long)c * RSZ;
    int v = base[idx];
    base[idx] = run;
    run += v;
  }
}

// ---------------- k7: scatter with LDS-atomic ranks -------------------------
__global__ void scatter_h(const int4* __restrict__ u4, const int4* __restrict__ i4,
                          int nV, const int* __restrict__ hist,
                          unsigned short* __restrict__ cols) {
  int r = blockIdx.x & (NR - 1), c = blockIdx.x >> 3;
  int lo = r * RSZ;
  __shared__ int pf[RSZ];
  const int* src = hist + (long)(r * NC + c) * RSZ;
  for (int i = threadIdx.x; i < RSZ; i += 256) pf[i] = src[i];
  __syncthreads();
  int cl = (nV + NC - 1) / NC;
  int p0 = c * cl, p1 = min(nV, p0 + cl);
  for (int p = p0 + (int)threadIdx.x; p < p1; p += 256) {
    int4 uu = u4[p], ii = i4[p];
    int a, pos;
    a = uu.x - lo; if ((unsigned)a < (unsigned)RSZ) { pos = atomicAdd(&pf[a], 1); cols[pos] = (unsigned short)(ii.x - kNU); }
    a = ii.x - lo; if ((unsigned)a < (unsigned)RSZ) { pos = atomicAdd(&pf[a], 1); cols[pos] = (unsigned short)uu.x; }
    a = uu.y - lo; if ((unsigned)a < (unsigned)RSZ) { pos = atomicAdd(&pf[a], 1); cols[pos] = (unsigned short)(ii.y - kNU); }
    a = ii.y - lo; if ((unsigned)a < (unsigned)RSZ) { pos = atomicAdd(&pf[a], 1); cols[pos] = (unsigned short)uu.y; }
    a = uu.z - lo; if ((unsigned)a < (unsigned)RSZ) { pos = atomicAdd(&pf[a], 1); cols[pos] = (unsigned short)(ii.z - kNU); }
    a = ii.z - lo; if ((unsigned)a < (unsigned)RSZ) { pos = atomicAdd(&pf[a], 1); cols[pos] = (unsigned short)uu.z; }
    a = uu.w - lo; if ((unsigned)a < (unsigned)RSZ) { pos = atomicAdd(&pf[a], 1); cols[pos] = (unsigned short)(ii.w - kNU); }
    a = ii.w - lo; if ((unsigned)a < (unsigned)RSZ) { pos = atomicAdd(&pf[a], 1); cols[pos] = (unsigned short)uu.w; }
  }
}

// ---------------- emb fp32 -> fp16 ------------------------------------------
__global__ void emb_to_h(const float4* __restrict__ in, H4* __restrict__ outp, int n) {
  int i = blockIdx.x * 256 + threadIdx.x;
  if (i < n) {
    float4 v = in[i];
    float2 lo = {v.x, v.y}, hi = {v.z, v.w};
    H4 o; o.lo = __float22half2_rn(lo); o.hi = __float22half2_rn(hi);
    outp[i] = o;
  }
}

// ---------------- feat SpMM, all nodes (merged): fp16 emb -> fp16 y~0 -------
__global__ void spmm_feat_all(const int* __restrict__ rs, const unsigned short* __restrict__ cols,
                              const H8* __restrict__ emb16, const float* __restrict__ rsDg,
                              H8* __restrict__ hU, H8* __restrict__ hI) {
  int row = blockIdx.x * 4 + (threadIdx.x >> 6);
  if (row >= kN) return;
  int lane = threadIdx.x & 63, g = lane >> 3, q = lane & 7;
  int s = rs[row], e = rs[row + 1];
  int base = (row < kNU) ? kNU : 0;   // emb idx = base + local col
  float a[8];
  #pragma unroll
  for (int k = 0; k < 8; ++k) a[k] = 0.f;
  int j = s + g;
  for (; j + 8 < e; j += 16) {
    int c0 = cols[j], c1 = cols[j + 8];
    H8 v0 = emb16[(long)(base + c0) * 8 + q];
    H8 v1 = emb16[(long)(base + c1) * 8 + q];
    #pragma unroll
    for (int k = 0; k < 4; ++k) {
      float2 f0 = __half22float2(v0.h[k]);
      float2 f1 = __half22float2(v1.h[k]);
      a[2 * k]     += f0.x + f1.x;
      a[2 * k + 1] += f0.y + f1.y;
    }
  }
  if (j < e) {
    int c = cols[j];
    H8 v = emb16[(long)(base + c) * 8 + q];
    #pragma unroll
    for (int k = 0; k < 4; ++k) {
      float2 f = __half22float2(v.h[k]);
      a[2 * k] += f.x; a[2 * k + 1] += f.y;
    }
  }
  #pragma unroll
  for (int m = 8; m <= 32; m <<= 1) {
    #pragma unroll
    for (int k = 0; k < 8; ++k) a[k] += __shfl_xor(a[k], m, 64);
  }
  if (g == 0) {
    H8 bv = emb16[(long)((row < kNU) ? 100000 : 100001) * 8 + q];
    float sc = rsDg[row] / (float)(e - s + 1);
    H8 o;
    #pragma unroll
    for (int k = 0; k < 4; ++k) {
      float2 bf = __half22float2(bv.h[k]);
      float2 f = {(a[2 * k] + bf.x) * sc, (a[2 * k + 1] + bf.y) * sc};
      o.h[k] = __float22half2_rn(f);
    }
    H8* dst = (row < kNU) ? (hU + (long)row * 8) : (hI + (long)(row - kNU) * 8);
    dst[q] = o;
  }
}

// ---------------- adj SpMM, all nodes (merged) ------------------------------
__global__ void spmm_adj_all(const int* __restrict__ rs, const unsigned short* __restrict__ cols,
                             const float* __restrict__ rsDg,
                             const H8* __restrict__ inU, const H8* __restrict__ inI,
                             H8* __restrict__ outU, H8* __restrict__ outI) {
  int row = blockIdx.x * 4 + (threadIdx.x >> 6);
  if (row >= kN) return;
  int lane = threadIdx.x & 63, g = lane >> 3, q = lane & 7;
  const H8* src = (row < kNU) ? inI : inU;   // cols are local to opposite half
  int s = rs[row], e = rs[row + 1];
  float a[8];
  #pragma unroll
  for (int k = 0; k < 8; ++k) a[k] = 0.f;
  int j = s + g;
  for (; j + 8 < e; j += 16) {
    int c0 = cols[j], c1 = cols[j + 8];
    H8 v0 = src[(long)c0 * 8 + q];
    H8 v1 = src[(long)c1 * 8 + q];
    #pragma unroll
    for (int k = 0; k < 4; ++k) {
      float2 f0 = __half22float2(v0.h[k]);
      float2 f1 = __half22float2(v1.h[k]);
      a[2 * k]     += f0.x + f1.x;
      a[2 * k + 1] += f0.y + f1.y;
    }
  }
  if (j < e) {
    int c = cols[j];
    H8 v = src[(long)c * 8 + q];
    #pragma unroll
    for (int k = 0; k < 4; ++k) {
      float2 f = __half22float2(v.h[k]);
      a[2 * k] += f.x; a[2 * k + 1] += f.y;
    }
  }
  #pragma unroll
  for (int m = 8; m <= 32; m <<= 1) {
    #pragma unroll
    for (int k = 0; k < 8; ++k) a[k] += __shfl_xor(a[k], m, 64);
  }
  if (g == 0) {
    float w = rsDg[row]; w = w * w;   // = 1/deg (deg>0); empty row -> 0 sum
    H8 o;
    #pragma unroll
    for (int k = 0; k < 4; ++k) {
      float2 f = {a[2 * k] * w, a[2 * k + 1] * w};
      o.h[k] = __float22half2_rn(f);
    }
    H8* dst = (row < kNU) ? (outU + (long)row * 8) : (outI + (long)(row - kNU) * 8);
    dst[q] = o;
  }
}

// ---------------- gathered-row accumulation (un-scale by sqrt(deg)) ---------
__global__ void acc_gather_h(const H8* __restrict__ hU, const H8* __restrict__ hI,
                             const int* __restrict__ deg,
                             const int* __restrict__ users, const int* __restrict__ pos,
                             const int* __restrict__ neg, float4* __restrict__ out, int add) {
  int gI = blockIdx.x * blockDim.x + threadIdx.x;
  if (gI >= 3 * kB * 8) return;
  int slot = gI >> 3, q = gI & 7;
  int which = slot >> 12, b = slot & (kB - 1);
  int node = which == 0 ? users[b] : (which == 1 ? pos[b] + kNU : neg[b] + kNU);
  H8 v = (node < kNU) ? hU[(long)node * 8 + q] : hI[(long)(node - kNU) * 8 + q];
  float sq = sqrtf((float)max(deg[node], 1));
  float2 f0 = __half22float2(v.h[0]), f1 = __half22float2(v.h[1]);
  float2 f2 = __half22float2(v.h[2]), f3 = __half22float2(v.h[3]);
  float4 r0 = {f0.x * sq, f0.y * sq, f1.x * sq, f1.y * sq};
  float4 r1 = {f2.x * sq, f2.y * sq, f3.x * sq, f3.y * sq};
  long o0 = (long)slot * 16 + q * 2;
  if (add) {
    float4 a0 = out[o0], a1 = out[o0 + 1];
    r0.x += a0.x; r0.y += a0.y; r0.z += a0.z; r0.w += a0.w;
    r1.x += a1.x; r1.y += a1.y; r1.z += a1.z; r1.w += a1.w;
  }
  out[o0] = r0; out[o0 + 1] = r1;
}

// ---------------- layer 3 restricted + /4 + per-row L2 ----------------------
__global__ void layer3_fin(const int* __restrict__ rs, const unsigned short* __restrict__ cols,
                           const float* __restrict__ rsDg,
                           const H8* __restrict__ hU, const H8* __restrict__ hI,
                           const int* __restrict__ users, const int* __restrict__ pos,
                           const int* __restrict__ neg,
                           float4* __restrict__ out, float* __restrict__ l2part) {
  int slot = blockIdx.x * 4 + (threadIdx.x >> 6);
  if (slot >= 3 * kB) return;
  int lane = threadIdx.x & 63, g = lane >> 3, q = lane & 7;
  int which = slot >> 12, b = slot & (kB - 1);
  int node = which == 0 ? users[b] : (which == 1 ? pos[b] + kNU : neg[b] + kNU);
  const H8* src = (node < kNU) ? hI : hU;
  int s = rs[node], e = rs[node + 1];
  float a[8];
  #pragma unroll
  for (int k = 0; k < 8; ++k) a[k] = 0.f;
  int j = s + g;
  for (; j + 8 < e; j += 16) {
    int c0 = cols[j], c1 = cols[j + 8];
    H8 v0 = src[(long)c0 * 8 + q];
    H8 v1 = src[(long)c1 * 8 + q];
    #pragma unroll
    for (int k = 0; k < 4; ++k) {
      float2 f0 = __half22float2(v0.h[k]);
      float2 f1 = __half22float2(v1.h[k]);
      a[2 * k]     += f0.x + f1.x;
      a[2 * k + 1] += f0.y + f1.y;
    }
  }
  if (j < e) {
    int c = cols[j];
    H8 v = src[(long)c * 8 + q];
    #pragma unroll
    for (int k = 0; k < 4; ++k) {
      float2 f = __half22float2(v.h[k]);
      a[2 * k] += f.x; a[2 * k + 1] += f.y;
    }
  }
  #pragma unroll
  for (int m = 8; m <= 32; m <<= 1) {
    #pragma unroll
    for (int k = 0; k < 8; ++k) a[k] += __shfl_xor(a[k], m, 64);
  }
  float t = 0.f;
  if (g == 0) {
    float sr = rsDg[node];   // y3 = rsDg * sum(in~)
    long o0 = (long)slot * 16 + q * 2;
    float4 a0 = out[o0], a1 = out[o0 + 1];
    float4 r0 = {(a0.x + a[0] * sr) * 0.25f, (a0.y + a[1] * sr) * 0.25f,
                 (a0.z + a[2] * sr) * 0.25f, (a0.w + a[3] * sr) * 0.25f};
    float4 r1 = {(a1.x + a[4] * sr) * 0.25f, (a1.y + a[5] * sr) * 0.25f,
                 (a1.z + a[6] * sr) * 0.25f, (a1.w + a[7] * sr) * 0.25f};
    out[o0] = r0; out[o0 + 1] = r1;
    t = r0.x * r0.x + r0.y * r0.y + r0.z * r0.z + r0.w * r0.w
      + r1.x * r1.x + r1.y * r1.y + r1.z * r1.z + r1.w * r1.w;
  }
  #pragma unroll
  for (int m = 1; m <= 4; m <<= 1) t += __shfl_xor(t, m, 64);
  if (lane == 0) l2part[slot] = t;
}

__global__ void l2_final(const float* __restrict__ l2part, float* __restrict__ outl2) {
  int b = blockIdx.x * blockDim.x + threadIdx.x;
  if (b < kB) outl2[b] = l2part[b] + l2part[kB + b] + l2part[2 * kB + b];
}

extern "C" void kernel_launch(void* const* d_in, const int* in_sizes, int n_in,
                              void* d_out, int out_size, void* d_ws, size_t ws_size,
                              hipStream_t stream) {
  const float* emb  = (const float*)d_in[0];
  const int*   arow = (const int*)d_in[3];
  const int*   users= (const int*)d_in[5];
  const int*   pos  = (const int*)d_in[6];
  const int*   neg  = (const int*)d_in[7];
  const int neA = in_sizes[3];              // 2,000,000
  const int nP  = neA / 2;                  // 1,000,000 pairs
  const int nV  = nP / 4;                   // 250,000 int4
  const int4* u4 = (const int4*)arow;
  const int4* i4 = (const int4*)(arow + nP);

  char* ws = (char*)d_ws;
  int*            degA     = (int*)(ws + 0);            // 400,000
  int*            rowStart = (int*)(ws + 400000);       // 400,004 (pad to 800128)
  float*          rsDg     = (float*)(ws + 800128);     // 400,000
  float*          l2part   = (float*)(ws + 1200128);    // 49,152
  int*            bsum     = (int*)(ws + 1249280);      // 1,024
  unsigned short* colA     = (unsigned short*)(ws + 1250304);  // 4,000,000
  __half*         emb16    = (__half*)(ws + 5250304);   // 12,800,256 -> 18,050,560
  // hist (25,600,000 B) ALIASES the state buffers: dead once scatter_h is done.
  int*            hist     = (int*)(ws + 18050560);
  __half*         hU0      = (__half*)(ws + 18050560);  // 7,680,000
  __half*         hU1      = (__half*)(ws + 25730560);  // 7,680,000
  __half*         hI0      = (__half*)(ws + 33410560);  // 5,120,000
  __half*         hI1      = (__half*)(ws + 38530560);  // 5,120,000 -> end 43,650,560

  float* out = (float*)d_out;
  const int NB = (kN + SCAN_CH - 1) / SCAN_CH;  // 49
  const int RG = (kN + 255) / 256;              // 391

  hist_k<<<NR * NC, 256, 0, stream>>>(u4, i4, nV, hist);
  degsum_k<<<RG, 256, 0, stream>>>(hist, degA, rsDg);
  scan_p1<<<NB, SCAN_T, 0, stream>>>(degA, kN, bsum);
  scan_p2<<<1, 64, 0, stream>>>(bsum, NB);
  scan_p3<<<NB, SCAN_T, 0, stream>>>(degA, kN, neA, bsum, rowStart);
  const int nE16 = 100002 * 16;   // float4 elements in emb
  emb_to_h<<<(nE16 + 255) / 256, 256, 0, stream>>>((const float4*)emb, (H4*)emb16, nE16);
  expand_k<<<RG, 256, 0, stream>>>(hist, rowStart);
  scatter_h<<<NR * NC, 256, 0, stream>>>(u4, i4, nV, hist, colA);

  const int GN = (kN + 3) / 4;   // 25000 blocks, 4 rows each

  // feature SpMM -> fp16 scaled state y~0 (overwrites hist region; hist dead)
  spmm_feat_all<<<GN, 256, 0, stream>>>(rowStart, colA, (const H8*)emb16, rsDg,
                                        (H8*)hU0, (H8*)hI0);
  acc_gather_h<<<(3 * kB * 8 + 255) / 256, 256, 0, stream>>>((const H8*)hU0, (const H8*)hI0,
      degA, users, pos, neg, (float4*)out, 0);

  // layer 1: (hU0,hI0) -> (hU1,hI1)
  spmm_adj_all<<<GN, 256, 0, stream>>>(rowStart, colA, rsDg, (const H8*)hU0, (const H8*)hI0,
                                       (H8*)hU1, (H8*)hI1);
  acc_gather_h<<<(3 * kB * 8 + 255) / 256, 256, 0, stream>>>((const H8*)hU1, (const H8*)hI1,
      degA, users, pos, neg, (float4*)out, 1);

  // layer 2: (hU1,hI1) -> (hU0,hI0)
  spmm_adj_all<<<GN, 256, 0, stream>>>(rowStart, colA, rsDg, (const H8*)hU1, (const H8*)hI1,
                                       (H8*)hU0, (H8*)hI0);
  acc_gather_h<<<(3 * kB * 8 + 255) / 256, 256, 0, stream>>>((const H8*)hU0, (const H8*)hI0,
      degA, users, pos, neg, (float4*)out, 1);

  // layer 3 restricted + epilogue (reads layer-2 state)
  layer3_fin<<<(3 * kB + 3) / 4, 256, 0, stream>>>(rowStart, colA, rsDg, (const H8*)hU0,
                                                   (const H8*)hI0, users, pos, neg,
                                                   (float4*)out, l2part);
  l2_final<<<(kB + 255) / 256, 256, 0, stream>>>(l2part, out + 3 * kB * 64);
}

// Round 12
// 223.836 us; speedup vs baseline: 1.6814x; 1.0156x over previous
//
#include <hip/hip_runtime.h>
#include <hip/hip_fp16.h>

// IGCN forward, round 12: round-11 structure (atomic-free histogram CSR build)
// + packed-fp16 accumulation in all SpMM inner loops (v_pk_add_f16: ~4x less
// VALU than cvt+f32-add; error shrunk by the 1/deg / rsqrt(deg) scaling).
//  k1: LDS histogram per (range,chunk) -> hist[r][c][localRow] (coalesced).
//  k2: row-sum hist -> deg, rsDg.   scan -> rowStart.
//  k6: in-place prefix over chunks + rowStart -> per-(row,chunk) base.
//  k7: re-stream pairs, LDS-atomic rank, plain u16 col stores. No global atomics.
//  hist (25.6MB) aliases the fp16 state buffers (dead until feat SpMM).

constexpr int kNU = 60000;
constexpr int kNI = 40000;
constexpr int kN  = 100000;
constexpr int kB  = 4096;
constexpr int NR  = 8,  RSZ = 12500;   // row ranges
constexpr int NC  = 64;                // chunks per range

struct alignas(16) H8 { __half2 h[4]; };   // 8 halfs = 16B
struct alignas(8)  H4 { __half2 lo, hi; }; // 4 halfs = 8B

// ---------------- k1: LDS histogram ----------------------------------------
__global__ void hist_k(const int4* __restrict__ u4, const int4* __restrict__ i4,
                       int nV, int* __restrict__ hist) {
  int r = blockIdx.x & (NR - 1), c = blockIdx.x >> 3;
  int lo = r * RSZ;
  __shared__ int h[RSZ];
  for (int i = threadIdx.x; i < RSZ; i += 256) h[i] = 0;
  __syncthreads();
  int cl = (nV + NC - 1) / NC;
  int p0 = c * cl, p1 = min(nV, p0 + cl);
  for (int p = p0 + (int)threadIdx.x; p < p1; p += 256) {
    int4 uu = u4[p], ii = i4[p];
    int a;
    a = uu.x - lo; if ((unsigned)a < (unsigned)RSZ) atomicAdd(&h[a], 1);
    a = ii.x - lo; if ((unsigned)a < (unsigned)RSZ) atomicAdd(&h[a], 1);
    a = uu.y - lo; if ((unsigned)a < (unsigned)RSZ) atomicAdd(&h[a], 1);
    a = ii.y - lo; if ((unsigned)a < (unsigned)RSZ) atomicAdd(&h[a], 1);
    a = uu.z - lo; if ((unsigned)a < (unsigned)RSZ) atomicAdd(&h[a], 1);
    a = ii.z - lo; if ((unsigned)a < (unsigned)RSZ) atomicAdd(&h[a], 1);
    a = uu.w - lo; if ((unsigned)a < (unsigned)RSZ) atomicAdd(&h[a], 1);
    a = ii.w - lo; if ((unsigned)a < (unsigned)RSZ) atomicAdd(&h[a], 1);
  }
  __syncthreads();
  int* dst = hist + (long)(r * NC + c) * RSZ;
  for (int i = threadIdx.x; i < RSZ; i += 256) dst[i] = h[i];
}

// ---------------- k2: deg = row-sum of hist; rsDg ---------------------------
__global__ void degsum_k(const int* __restrict__ hist, int* __restrict__ deg,
                         float* __restrict__ rsDg) {
  int row = blockIdx.x * 256 + threadIdx.x;
  if (row >= kN) return;
  int r = row / RSZ, local = row - r * RSZ;
  const int* base = hist + (long)r * NC * RSZ + local;
  int s = 0;
  for (int c = 0; c < NC; ++c) s += base[(long)c * RSZ];
  deg[row] = s;
  rsDg[row] = s > 0 ? rsqrtf((float)s) : 1.f;
}

// ---------------- scan (rowStart from deg) ----------------------------------
constexpr int SCAN_T = 256, SCAN_E = 8, SCAN_CH = SCAN_T * SCAN_E;  // 2048

__global__ void scan_p1(const int* __restrict__ in, int n, int* __restrict__ bsum) {
  __shared__ int lds[SCAN_T];
  int t = threadIdx.x;
  int base = blockIdx.x * SCAN_CH + t * SCAN_E;
  int s = 0;
  #pragma unroll
  for (int k = 0; k < SCAN_E; ++k) { int i = base + k; if (i < n) s += in[i]; }
  lds[t] = s; __syncthreads();
  for (int off = SCAN_T / 2; off; off >>= 1) {
    if (t < off) lds[t] += lds[t + off];
    __syncthreads();
  }
  if (t == 0) bsum[blockIdx.x] = lds[0];
}

__global__ void scan_p2(int* bsum, int nb) {
  if (threadIdx.x == 0 && blockIdx.x == 0) {
    int run = 0;
    for (int i = 0; i < nb; ++i) { int v = bsum[i]; bsum[i] = run; run += v; }
  }
}

__global__ void scan_p3(const int* __restrict__ in, int n, int ntot,
                        const int* __restrict__ bsum, int* __restrict__ out) {
  __shared__ int lds[SCAN_T];
  int t = threadIdx.x;
  int base = blockIdx.x * SCAN_CH + t * SCAN_E;
  int v[SCAN_E]; int s = 0;
  #pragma unroll
  for (int k = 0; k < SCAN_E; ++k) { int i = base + k; v[k] = (i < n) ? in[i] : 0; s += v[k]; }
  lds[t] = s; __syncthreads();
  for (int off = 1; off < SCAN_T; off <<= 1) {
    int x = (t >= off) ? lds[t - off] : 0;
    __syncthreads();
    lds[t] += x;
    __syncthreads();
  }
  int pre = lds[t] - s + bsum[blockIdx.x];
  #pragma unroll
  for (int k = 0; k < SCAN_E; ++k) {
    int i = base + k;
    if (i < n) { out[i] = pre; pre += v[k]; }
  }
  if (blockIdx.x == 0 && t == 0) out[n] = ntot;
}

// ---------------- k6: expand hist -> per-(row,chunk) base (in place) --------
__global__ void expand_k(int* __restrict__ hist, const int* __restrict__ rowStart) {
  int row = blockIdx.x * 256 + threadIdx.x;
  if (row >= kN) return;
  int r = row / RSZ, local = row - r * RSZ;
  int* base = hist + (long)r * NC * RSZ + local;
  int run = rowStart[row];
  for (int c = 0; c < NC; ++c) {
    long idx = (long)c * RSZ;
    int v = base[idx];
    base[idx] = run;
    run += v;
  }
}

// ---------------- k7: scatter with LDS-atomic ranks -------------------------
__global__ void scatter_h(const int4* __restrict__ u4, const int4* __restrict__ i4,
                          int nV, const int* __restrict__ hist,
                          unsigned short* __restrict__ cols) {
  int r = blockIdx.x & (NR - 1), c = blockIdx.x >> 3;
  int lo = r * RSZ;
  __shared__ int pf[RSZ];
  const int* src = hist + (long)(r * NC + c) * RSZ;
  for (int i = threadIdx.x; i < RSZ; i += 256) pf[i] = src[i];
  __syncthreads();
  int cl = (nV + NC - 1) / NC;
  int p0 = c * cl, p1 = min(nV, p0 + cl);
  for (int p = p0 + (int)threadIdx.x; p < p1; p += 256) {
    int4 uu = u4[p], ii = i4[p];
    int a, pos;
    a = uu.x - lo; if ((unsigned)a < (unsigned)RSZ) { pos = atomicAdd(&pf[a], 1); cols[pos] = (unsigned short)(ii.x - kNU); }
    a = ii.x - lo; if ((unsigned)a < (unsigned)RSZ) { pos = atomicAdd(&pf[a], 1); cols[pos] = (unsigned short)uu.x; }
    a = uu.y - lo; if ((unsigned)a < (unsigned)RSZ) { pos = atomicAdd(&pf[a], 1); cols[pos] = (unsigned short)(ii.y - kNU); }
    a = ii.y - lo; if ((unsigned)a < (unsigned)RSZ) { pos = atomicAdd(&pf[a], 1); cols[pos] = (unsigned short)uu.y; }
    a = uu.z - lo; if ((unsigned)a < (unsigned)RSZ) { pos = atomicAdd(&pf[a], 1); cols[pos] = (unsigned short)(ii.z - kNU); }
    a = ii.z - lo; if ((unsigned)a < (unsigned)RSZ) { pos = atomicAdd(&pf[a], 1); cols[pos] = (unsigned short)uu.z; }
    a = uu.w - lo; if ((unsigned)a < (unsigned)RSZ) { pos = atomicAdd(&pf[a], 1); cols[pos] = (unsigned short)(ii.w - kNU); }
    a = ii.w - lo; if ((unsigned)a < (unsigned)RSZ) { pos = atomicAdd(&pf[a], 1); cols[pos] = (unsigned short)uu.w; }
  }
}

// ---------------- emb fp32 -> fp16 ------------------------------------------
__global__ void emb_to_h(const float4* __restrict__ in, H4* __restrict__ outp, int n) {
  int i = blockIdx.x * 256 + threadIdx.x;
  if (i < n) {
    float4 v = in[i];
    float2 lo = {v.x, v.y}, hi = {v.z, v.w};
    H4 o; o.lo = __float22half2_rn(lo); o.hi = __float22half2_rn(hi);
    outp[i] = o;
  }
}

// ---------------- feat SpMM (merged): fp16 emb, packed-fp16 accum -----------
__global__ void spmm_feat_all(const int* __restrict__ rs, const unsigned short* __restrict__ cols,
                              const H8* __restrict__ emb16, const float* __restrict__ rsDg,
                              H8* __restrict__ hU, H8* __restrict__ hI) {
  int row = blockIdx.x * 4 + (threadIdx.x >> 6);
  if (row >= kN) return;
  int lane = threadIdx.x & 63, g = lane >> 3, q = lane & 7;
  int s = rs[row], e = rs[row + 1];
  int base = (row < kNU) ? kNU : 0;   // emb idx = base + local col
  __half2 z = __float2half2_rn(0.f);
  __half2 hacc[4] = {z, z, z, z};
  int j = s + g;
  for (; j + 8 < e; j += 16) {
    int c0 = cols[j], c1 = cols[j + 8];
    H8 v0 = emb16[(long)(base + c0) * 8 + q];
    H8 v1 = emb16[(long)(base + c1) * 8 + q];
    #pragma unroll
    for (int k = 0; k < 4; ++k)
      hacc[k] = __hadd2(hacc[k], __hadd2(v0.h[k], v1.h[k]));
  }
  if (j < e) {
    int c = cols[j];
    H8 v = emb16[(long)(base + c) * 8 + q];
    #pragma unroll
    for (int k = 0; k < 4; ++k) hacc[k] = __hadd2(hacc[k], v.h[k]);
  }
  float a[8];
  #pragma unroll
  for (int k = 0; k < 4; ++k) {
    float2 f = __half22float2(hacc[k]);
    a[2 * k] = f.x; a[2 * k + 1] = f.y;
  }
  #pragma unroll
  for (int m = 8; m <= 32; m <<= 1) {
    #pragma unroll
    for (int k = 0; k < 8; ++k) a[k] += __shfl_xor(a[k], m, 64);
  }
  if (g == 0) {
    H8 bv = emb16[(long)((row < kNU) ? 100000 : 100001) * 8 + q];
    float sc = rsDg[row] / (float)(e - s + 1);
    H8 o;
    #pragma unroll
    for (int k = 0; k < 4; ++k) {
      float2 bf = __half22float2(bv.h[k]);
      float2 f = {(a[2 * k] + bf.x) * sc, (a[2 * k + 1] + bf.y) * sc};
      o.h[k] = __float22half2_rn(f);
    }
    H8* dst = (row < kNU) ? (hU + (long)row * 8) : (hI + (long)(row - kNU) * 8);
    dst[q] = o;
  }
}

// ---------------- adj SpMM (merged): packed-fp16 accum ----------------------
__global__ void spmm_adj_all(const int* __restrict__ rs, const unsigned short* __restrict__ cols,
                             const float* __restrict__ rsDg,
                             const H8* __restrict__ inU, const H8* __restrict__ inI,
                             H8* __restrict__ outU, H8* __restrict__ outI) {
  int row = blockIdx.x * 4 + (threadIdx.x >> 6);
  if (row >= kN) return;
  int lane = threadIdx.x & 63, g = lane >> 3, q = lane & 7;
  const H8* src = (row < kNU) ? inI : inU;   // cols are local to opposite half
  int s = rs[row], e = rs[row + 1];
  __half2 z = __float2half2_rn(0.f);
  __half2 hacc[4] = {z, z, z, z};
  int j = s + g;
  for (; j + 8 < e; j += 16) {
    int c0 = cols[j], c1 = cols[j + 8];
    H8 v0 = src[(long)c0 * 8 + q];
    H8 v1 = src[(long)c1 * 8 + q];
    #pragma unroll
    for (int k = 0; k < 4; ++k)
      hacc[k] = __hadd2(hacc[k], __hadd2(v0.h[k], v1.h[k]));
  }
  if (j < e) {
    int c = cols[j];
    H8 v = src[(long)c * 8 + q];
    #pragma unroll
    for (int k = 0; k < 4; ++k) hacc[k] = __hadd2(hacc[k], v.h[k]);
  }
  float a[8];
  #pragma unroll
  for (int k = 0; k < 4; ++k) {
    float2 f = __half22float2(hacc[k]);
    a[2 * k] = f.x; a[2 * k + 1] = f.y;
  }
  #pragma unroll
  for (int m = 8; m <= 32; m <<= 1) {
    #pragma unroll
    for (int k = 0; k < 8; ++k) a[k] += __shfl_xor(a[k], m, 64);
  }
  if (g == 0) {
    float w = rsDg[row]; w = w * w;   // = 1/deg (deg>0); empty row -> 0 sum
    H8 o;
    #pragma unroll
    for (int k = 0; k < 4; ++k) {
      float2 f = {a[2 * k] * w, a[2 * k + 1] * w};
      o.h[k] = __float22half2_rn(f);
    }
    H8* dst = (row < kNU) ? (outU + (long)row * 8) : (outI + (long)(row - kNU) * 8);
    dst[q] = o;
  }
}

// ---------------- gathered-row accumulation (un-scale by sqrt(deg)) ---------
__global__ void acc_gather_h(const H8* __restrict__ hU, const H8* __restrict__ hI,
                             const int* __restrict__ deg,
                             const int* __restrict__ users, const int* __restrict__ pos,
                             const int* __restrict__ neg, float4* __restrict__ out, int add) {
  int gI = blockIdx.x * blockDim.x + threadIdx.x;
  if (gI >= 3 * kB * 8) return;
  int slot = gI >> 3, q = gI & 7;
  int which = slot >> 12, b = slot & (kB - 1);
  int node = which == 0 ? users[b] : (which == 1 ? pos[b] + kNU : neg[b] + kNU);
  H8 v = (node < kNU) ? hU[(long)node * 8 + q] : hI[(long)(node - kNU) * 8 + q];
  float sq = sqrtf((float)max(deg[node], 1));
  float2 f0 = __half22float2(v.h[0]), f1 = __half22float2(v.h[1]);
  float2 f2 = __half22float2(v.h[2]), f3 = __half22float2(v.h[3]);
  float4 r0 = {f0.x * sq, f0.y * sq, f1.x * sq, f1.y * sq};
  float4 r1 = {f2.x * sq, f2.y * sq, f3.x * sq, f3.y * sq};
  long o0 = (long)slot * 16 + q * 2;
  if (add) {
    float4 a0 = out[o0], a1 = out[o0 + 1];
    r0.x += a0.x; r0.y += a0.y; r0.z += a0.z; r0.w += a0.w;
    r1.x += a1.x; r1.y += a1.y; r1.z += a1.z; r1.w += a1.w;
  }
  out[o0] = r0; out[o0 + 1] = r1;
}

// ---------------- layer 3 restricted + /4 + per-row L2 ----------------------
__global__ void layer3_fin(const int* __restrict__ rs, const unsigned short* __restrict__ cols,
                           const float* __restrict__ rsDg,
                           const H8* __restrict__ hU, const H8* __restrict__ hI,
                           const int* __restrict__ users, const int* __restrict__ pos,
                           const int* __restrict__ neg,
                           float4* __restrict__ out, float* __restrict__ l2part) {
  int slot = blockIdx.x * 4 + (threadIdx.x >> 6);
  if (slot >= 3 * kB) return;
  int lane = threadIdx.x & 63, g = lane >> 3, q = lane & 7;
  int which = slot >> 12, b = slot & (kB - 1);
  int node = which == 0 ? users[b] : (which == 1 ? pos[b] + kNU : neg[b] + kNU);
  const H8* src = (node < kNU) ? hI : hU;
  int s = rs[node], e = rs[node + 1];
  __half2 z = __float2half2_rn(0.f);
  __half2 hacc[4] = {z, z, z, z};
  int j = s + g;
  for (; j + 8 < e; j += 16) {
    int c0 = cols[j], c1 = cols[j + 8];
    H8 v0 = src[(long)c0 * 8 + q];
    H8 v1 = src[(long)c1 * 8 + q];
    #pragma unroll
    for (int k = 0; k < 4; ++k)
      hacc[k] = __hadd2(hacc[k], __hadd2(v0.h[k], v1.h[k]));
  }
  if (j < e) {
    int c = cols[j];
    H8 v = src[(long)c * 8 + q];
    #pragma unroll
    for (int k = 0; k < 4; ++k) hacc[k] = __hadd2(hacc[k], v.h[k]);
  }
  float a[8];
  #pragma unroll
  for (int k = 0; k < 4; ++k) {
    float2 f = __half22float2(hacc[k]);
    a[2 * k] = f.x; a[2 * k + 1] = f.y;
  }
  #pragma unroll
  for (int m = 8; m <= 32; m <<= 1) {
    #pragma unroll
    for (int k = 0; k < 8; ++k) a[k] += __shfl_xor(a[k], m, 64);
  }
  float t = 0.f;
  if (g == 0) {
    float sr = rsDg[node];   // y3 = rsDg * sum(in~)
    long o0 = (long)slot * 16 + q * 2;
    float4 a0 = out[o0], a1 = out[o0 + 1];
    float4 r0 = {(a0.x + a[0] * sr) * 0.25f, (a0.y + a[1] * sr) * 0.25f,
                 (a0.z + a[2] * sr) * 0.25f, (a0.w + a[3] * sr) * 0.25f};
    float4 r1 = {(a1.x + a[4] * sr) * 0.25f, (a1.y + a[5] * sr) * 0.25f,
                 (a1.z + a[6] * sr) * 0.25f, (a1.w + a[7] * sr) * 0.25f};
    out[o0] = r0; out[o0 + 1] = r1;
    t = r0.x * r0.x + r0.y * r0.y + r0.z * r0.z + r0.w * r0.w
      + r1.x * r1.x + r1.y * r1.y + r1.z * r1.z + r1.w * r1.w;
  }
  #pragma unroll
  for (int m = 1; m <= 4; m <<= 1) t += __shfl_xor(t, m, 64);
  if (lane == 0) l2part[slot] = t;
}

__global__ void l2_final(const float* __restrict__ l2part, float* __restrict__ outl2) {
  int b = blockIdx.x * blockDim.x + threadIdx.x;
  if (b < kB) outl2[b] = l2part[b] + l2part[kB + b] + l2part[2 * kB + b];
}

extern "C" void kernel_launch(void* const* d_in, const int* in_sizes, int n_in,
                              void* d_out, int out_size, void* d_ws, size_t ws_size,
                              hipStream_t stream) {
  const float* emb  = (const float*)d_in[0];
  const int*   arow = (const int*)d_in[3];
  const int*   users= (const int*)d_in[5];
  const int*   pos  = (const int*)d_in[6];
  const int*   neg  = (const int*)d_in[7];
  const int neA = in_sizes[3];              // 2,000,000
  const int nP  = neA / 2;                  // 1,000,000 pairs
  const int nV  = nP / 4;                   // 250,000 int4
  const int4* u4 = (const int4*)arow;
  const int4* i4 = (const int4*)(arow + nP);

  char* ws = (char*)d_ws;
  int*            degA     = (int*)(ws + 0);            // 400,000
  int*            rowStart = (int*)(ws + 400000);       // 400,004 (pad to 800128)
  float*          rsDg     = (float*)(ws + 800128);     // 400,000
  float*          l2part   = (float*)(ws + 1200128);    // 49,152
  int*            bsum     = (int*)(ws + 1249280);      // 1,024
  unsigned short* colA     = (unsigned short*)(ws + 1250304);  // 4,000,000
  __half*         emb16    = (__half*)(ws + 5250304);   // 12,800,256 -> 18,050,560
  // hist (25,600,000 B) ALIASES the state buffers: dead once scatter_h is done.
  int*            hist     = (int*)(ws + 18050560);
  __half*         hU0      = (__half*)(ws + 18050560);  // 7,680,000
  __half*         hU1      = (__half*)(ws + 25730560);  // 7,680,000
  __half*         hI0      = (__half*)(ws + 33410560);  // 5,120,000
  __half*         hI1      = (__half*)(ws + 38530560);  // 5,120,000 -> end 43,650,560

  float* out = (float*)d_out;
  const int NB = (kN + SCAN_CH - 1) / SCAN_CH;  // 49
  const int RG = (kN + 255) / 256;              // 391

  hist_k<<<NR * NC, 256, 0, stream>>>(u4, i4, nV, hist);
  degsum_k<<<RG, 256, 0, stream>>>(hist, degA, rsDg);
  scan_p1<<<NB, SCAN_T, 0, stream>>>(degA, kN, bsum);
  scan_p2<<<1, 64, 0, stream>>>(bsum, NB);
  scan_p3<<<NB, SCAN_T, 0, stream>>>(degA, kN, neA, bsum, rowStart);
  const int nE16 = 100002 * 16;   // float4 elements in emb
  emb_to_h<<<(nE16 + 255) / 256, 256, 0, stream>>>((const float4*)emb, (H4*)emb16, nE16);
  expand_k<<<RG, 256, 0, stream>>>(hist, rowStart);
  scatter_h<<<NR * NC, 256, 0, stream>>>(u4, i4, nV, hist, colA);

  const int GN = (kN + 3) / 4;   // 25000 blocks, 4 rows each

  // feature SpMM -> fp16 scaled state y~0 (overwrites hist region; hist dead)
  spmm_feat_all<<<GN, 256, 0, stream>>>(rowStart, colA, (const H8*)emb16, rsDg,
                                        (H8*)hU0, (H8*)hI0);
  acc_gather_h<<<(3 * kB * 8 + 255) / 256, 256, 0, stream>>>((const H8*)hU0, (const H8*)hI0,
      degA, users, pos, neg, (float4*)out, 0);

  // layer 1: (hU0,hI0) -> (hU1,hI1)
  spmm_adj_all<<<GN, 256, 0, stream>>>(rowStart, colA, rsDg, (const H8*)hU0, (const H8*)hI0,
                                       (H8*)hU1, (H8*)hI1);
  acc_gather_h<<<(3 * kB * 8 + 255) / 256, 256, 0, stream>>>((const H8*)hU1, (const H8*)hI1,
      degA, users, pos, neg, (float4*)out, 1);

  // layer 2: (hU1,hI1) -> (hU0,hI0)
  spmm_adj_all<<<GN, 256, 0, stream>>>(rowStart, colA, rsDg, (const H8*)hU1, (const H8*)hI1,
                                       (H8*)hU0, (H8*)hI0);
  acc_gather_h<<<(3 * kB * 8 + 255) / 256, 256, 0, stream>>>((const H8*)hU0, (const H8*)hI0,
      degA, users, pos, neg, (float4*)out, 1);

  // layer 3 restricted + epilogue (reads layer-2 state)
  layer3_fin<<<(3 * kB + 3) / 4, 256, 0, stream>>>(rowStart, colA, rsDg, (const H8*)hU0,
                                                   (const H8*)hI0, users, pos, neg,
                                                   (float4*)out, l2part);
  l2_final<<<(kB + 255) / 256, 256, 0, stream>>>(l2part, out + 3 * kB * 64);
}

// Round 13
// 193.532 us; speedup vs baseline: 1.9447x; 1.1566x over previous
//
#include <hip/hip_runtime.h>
#include <hip/hip_fp16.h>

// IGCN forward, round 13: round-12 base (atomic-free histogram CSR build,
// fp16 state, u16 local cols, packed-fp16 accum) with feat/adj SpMM
// restructured as wave = 8 rows x 8 dim-lanes, SERIAL per-row accumulation:
// no cross-lane reduction (was 24 shfl + wave-wide load barrier per row),
// 1KB contiguous stores per wave, loads pipeline freely across iterations.

constexpr int kNU = 60000;
constexpr int kNI = 40000;
constexpr int kN  = 100000;
constexpr int kB  = 4096;
constexpr int NR  = 8,  RSZ = 12500;   // row ranges
constexpr int NC  = 64;                // chunks per range

struct alignas(16) H8 { __half2 h[4]; };   // 8 halfs = 16B
struct alignas(8)  H4 { __half2 lo, hi; }; // 4 halfs = 8B

// ---------------- k1: LDS histogram ----------------------------------------
__global__ void hist_k(const int4* __restrict__ u4, const int4* __restrict__ i4,
                       int nV, int* __restrict__ hist) {
  int r = blockIdx.x & (NR - 1), c = blockIdx.x >> 3;
  int lo = r * RSZ;
  __shared__ int h[RSZ];
  for (int i = threadIdx.x; i < RSZ; i += 256) h[i] = 0;
  __syncthreads();
  int cl = (nV + NC - 1) / NC;
  int p0 = c * cl, p1 = min(nV, p0 + cl);
  for (int p = p0 + (int)threadIdx.x; p < p1; p += 256) {
    int4 uu = u4[p], ii = i4[p];
    int a;
    a = uu.x - lo; if ((unsigned)a < (unsigned)RSZ) atomicAdd(&h[a], 1);
    a = ii.x - lo; if ((unsigned)a < (unsigned)RSZ) atomicAdd(&h[a], 1);
    a = uu.y - lo; if ((unsigned)a < (unsigned)RSZ) atomicAdd(&h[a], 1);
    a = ii.y - lo; if ((unsigned)a < (unsigned)RSZ) atomicAdd(&h[a], 1);
    a = uu.z - lo; if ((unsigned)a < (unsigned)RSZ) atomicAdd(&h[a], 1);
    a = ii.z - lo; if ((unsigned)a < (unsigned)RSZ) atomicAdd(&h[a], 1);
    a = uu.w - lo; if ((unsigned)a < (unsigned)RSZ) atomicAdd(&h[a], 1);
    a = ii.w - lo; if ((unsigned)a < (unsigned)RSZ) atomicAdd(&h[a], 1);
  }
  __syncthreads();
  int* dst = hist + (long)(r * NC + c) * RSZ;
  for (int i = threadIdx.x; i < RSZ; i += 256) dst[i] = h[i];
}

// ---------------- k2: deg = row-sum of hist; rsDg ---------------------------
__global__ void degsum_k(const int* __restrict__ hist, int* __restrict__ deg,
                         float* __restrict__ rsDg) {
  int row = blockIdx.x * 256 + threadIdx.x;
  if (row >= kN) return;
  int r = row / RSZ, local = row - r * RSZ;
  const int* base = hist + (long)r * NC * RSZ + local;
  int s = 0;
  for (int c = 0; c < NC; ++c) s += base[(long)c * RSZ];
  deg[row] = s;
  rsDg[row] = s > 0 ? rsqrtf((float)s) : 1.f;
}

// ---------------- scan (rowStart from deg) ----------------------------------
constexpr int SCAN_T = 256, SCAN_E = 8, SCAN_CH = SCAN_T * SCAN_E;  // 2048

__global__ void scan_p1(const int* __restrict__ in, int n, int* __restrict__ bsum) {
  __shared__ int lds[SCAN_T];
  int t = threadIdx.x;
  int base = blockIdx.x * SCAN_CH + t * SCAN_E;
  int s = 0;
  #pragma unroll
  for (int k = 0; k < SCAN_E; ++k) { int i = base + k; if (i < n) s += in[i]; }
  lds[t] = s; __syncthreads();
  for (int off = SCAN_T / 2; off; off >>= 1) {
    if (t < off) lds[t] += lds[t + off];
    __syncthreads();
  }
  if (t == 0) bsum[blockIdx.x] = lds[0];
}

__global__ void scan_p2(int* bsum, int nb) {
  if (threadIdx.x == 0 && blockIdx.x == 0) {
    int run = 0;
    for (int i = 0; i < nb; ++i) { int v = bsum[i]; bsum[i] = run; run += v; }
  }
}

__global__ void scan_p3(const int* __restrict__ in, int n, int ntot,
                        const int* __restrict__ bsum, int* __restrict__ out) {
  __shared__ int lds[SCAN_T];
  int t = threadIdx.x;
  int base = blockIdx.x * SCAN_CH + t * SCAN_E;
  int v[SCAN_E]; int s = 0;
  #pragma unroll
  for (int k = 0; k < SCAN_E; ++k) { int i = base + k; v[k] = (i < n) ? in[i] : 0; s += v[k]; }
  lds[t] = s; __syncthreads();
  for (int off = 1; off < SCAN_T; off <<= 1) {
    int x = (t >= off) ? lds[t - off] : 0;
    __syncthreads();
    lds[t] += x;
    __syncthreads();
  }
  int pre = lds[t] - s + bsum[blockIdx.x];
  #pragma unroll
  for (int k = 0; k < SCAN_E; ++k) {
    int i = base + k;
    if (i < n) { out[i] = pre; pre += v[k]; }
  }
  if (blockIdx.x == 0 && t == 0) out[n] = ntot;
}

// ---------------- k6: expand hist -> per-(row,chunk) base (in place) --------
__global__ void expand_k(int* __restrict__ hist, const int* __restrict__ rowStart) {
  int row = blockIdx.x * 256 + threadIdx.x;
  if (row >= kN) return;
  int r = row / RSZ, local = row - r * RSZ;
  int* base = hist + (long)r * NC * RSZ + local;
  int run = rowStart[row];
  for (int c = 0; c < NC; ++c) {
    long idx = (long)c * RSZ;
    int v = base[idx];
    base[idx] = run;
    run += v;
  }
}

// ---------------- k7: scatter with LDS-atomic ranks -------------------------
__global__ void scatter_h(const int4* __restrict__ u4, const int4* __restrict__ i4,
                          int nV, const int* __restrict__ hist,
                          unsigned short* __restrict__ cols) {
  int r = blockIdx.x & (NR - 1), c = blockIdx.x >> 3;
  int lo = r * RSZ;
  __shared__ int pf[RSZ];
  const int* src = hist + (long)(r * NC + c) * RSZ;
  for (int i = threadIdx.x; i < RSZ; i += 256) pf[i] = src[i];
  __syncthreads();
  int cl = (nV + NC - 1) / NC;
  int p0 = c * cl, p1 = min(nV, p0 + cl);
  for (int p = p0 + (int)threadIdx.x; p < p1; p += 256) {
    int4 uu = u4[p], ii = i4[p];
    int a, pos;
    a = uu.x - lo; if ((unsigned)a < (unsigned)RSZ) { pos = atomicAdd(&pf[a], 1); cols[pos] = (unsigned short)(ii.x - kNU); }
    a = ii.x - lo; if ((unsigned)a < (unsigned)RSZ) { pos = atomicAdd(&pf[a], 1); cols[pos] = (unsigned short)uu.x; }
    a = uu.y - lo; if ((unsigned)a < (unsigned)RSZ) { pos = atomicAdd(&pf[a], 1); cols[pos] = (unsigned short)(ii.y - kNU); }
    a = ii.y - lo; if ((unsigned)a < (unsigned)RSZ) { pos = atomicAdd(&pf[a], 1); cols[pos] = (unsigned short)uu.y; }
    a = uu.z - lo; if ((unsigned)a < (unsigned)RSZ) { pos = atomicAdd(&pf[a], 1); cols[pos] = (unsigned short)(ii.z - kNU); }
    a = ii.z - lo; if ((unsigned)a < (unsigned)RSZ) { pos = atomicAdd(&pf[a], 1); cols[pos] = (unsigned short)uu.z; }
    a = uu.w - lo; if ((unsigned)a < (unsigned)RSZ) { pos = atomicAdd(&pf[a], 1); cols[pos] = (unsigned short)(ii.w - kNU); }
    a = ii.w - lo; if ((unsigned)a < (unsigned)RSZ) { pos = atomicAdd(&pf[a], 1); cols[pos] = (unsigned short)uu.w; }
  }
}

// ---------------- emb fp32 -> fp16 ------------------------------------------
__global__ void emb_to_h(const float4* __restrict__ in, H4* __restrict__ outp, int n) {
  int i = blockIdx.x * 256 + threadIdx.x;
  if (i < n) {
    float4 v = in[i];
    float2 lo = {v.x, v.y}, hi = {v.z, v.w};
    H4 o; o.lo = __float22half2_rn(lo); o.hi = __float22half2_rn(hi);
    outp[i] = o;
  }
}

// ---------------- feat SpMM: wave = 8 rows x 8 dim-lanes, serial ------------
__global__ void spmm_feat_all(const int* __restrict__ rs, const unsigned short* __restrict__ cols,
                              const H8* __restrict__ emb16, const float* __restrict__ rsDg,
                              H8* __restrict__ hU, H8* __restrict__ hI) {
  int lane = threadIdx.x & 63, wid = threadIdx.x >> 6;
  int rg = lane >> 3, q = lane & 7;
  int row = blockIdx.x * 32 + wid * 8 + rg;
  if (row >= kN) return;
  int s = rs[row], e = rs[row + 1];
  int base = (row < kNU) ? kNU : 0;   // emb idx = base + local col
  __half2 z = __float2half2_rn(0.f);
  __half2 hacc[4] = {z, z, z, z};
  int j = s;
  for (; j + 1 < e; j += 2) {
    int c0 = cols[j], c1 = cols[j + 1];
    H8 v0 = emb16[(long)(base + c0) * 8 + q];
    H8 v1 = emb16[(long)(base + c1) * 8 + q];
    #pragma unroll
    for (int k = 0; k < 4; ++k)
      hacc[k] = __hadd2(hacc[k], __hadd2(v0.h[k], v1.h[k]));
  }
  if (j < e) {
    int c = cols[j];
    H8 v = emb16[(long)(base + c) * 8 + q];
    #pragma unroll
    for (int k = 0; k < 4; ++k) hacc[k] = __hadd2(hacc[k], v.h[k]);
  }
  H8 bv = emb16[(long)((row < kNU) ? 100000 : 100001) * 8 + q];
  float sc = rsDg[row] / (float)(e - s + 1);
  H8 o;
  #pragma unroll
  for (int k = 0; k < 4; ++k) {
    float2 f = __half22float2(hacc[k]);
    float2 bf = __half22float2(bv.h[k]);
    float2 r = {(f.x + bf.x) * sc, (f.y + bf.y) * sc};
    o.h[k] = __float22half2_rn(r);
  }
  if (row < kNU) hU[(long)row * 8 + q] = o;
  else           hI[(long)(row - kNU) * 8 + q] = o;
}

// ---------------- adj SpMM: wave = 8 rows x 8 dim-lanes, serial -------------
__global__ void spmm_adj_all(const int* __restrict__ rs, const unsigned short* __restrict__ cols,
                             const float* __restrict__ rsDg,
                             const H8* __restrict__ inU, const H8* __restrict__ inI,
                             H8* __restrict__ outU, H8* __restrict__ outI) {
  int lane = threadIdx.x & 63, wid = threadIdx.x >> 6;
  int rg = lane >> 3, q = lane & 7;
  int row = blockIdx.x * 32 + wid * 8 + rg;
  if (row >= kN) return;
  const H8* src = (row < kNU) ? inI : inU;   // cols are local to opposite half
  int s = rs[row], e = rs[row + 1];
  __half2 z = __float2half2_rn(0.f);
  __half2 hacc[4] = {z, z, z, z};
  int j = s;
  for (; j + 1 < e; j += 2) {
    int c0 = cols[j], c1 = cols[j + 1];
    H8 v0 = src[(long)c0 * 8 + q];
    H8 v1 = src[(long)c1 * 8 + q];
    #pragma unroll
    for (int k = 0; k < 4; ++k)
      hacc[k] = __hadd2(hacc[k], __hadd2(v0.h[k], v1.h[k]));
  }
  if (j < e) {
    int c = cols[j];
    H8 v = src[(long)c * 8 + q];
    #pragma unroll
    for (int k = 0; k < 4; ++k) hacc[k] = __hadd2(hacc[k], v.h[k]);
  }
  float w = rsDg[row]; w = w * w;   // = 1/deg (deg>0); empty row -> 0 sum
  H8 o;
  #pragma unroll
  for (int k = 0; k < 4; ++k) {
    float2 f = __half22float2(hacc[k]);
    float2 r = {f.x * w, f.y * w};
    o.h[k] = __float22half2_rn(r);
  }
  if (row < kNU) outU[(long)row * 8 + q] = o;
  else           outI[(long)(row - kNU) * 8 + q] = o;
}

// ---------------- gathered-row accumulation (un-scale by sqrt(deg)) ---------
__global__ void acc_gather_h(const H8* __restrict__ hU, const H8* __restrict__ hI,
                             const int* __restrict__ deg,
                             const int* __restrict__ users, const int* __restrict__ pos,
                             const int* __restrict__ neg, float4* __restrict__ out, int add) {
  int gI = blockIdx.x * blockDim.x + threadIdx.x;
  if (gI >= 3 * kB * 8) return;
  int slot = gI >> 3, q = gI & 7;
  int which = slot >> 12, b = slot & (kB - 1);
  int node = which == 0 ? users[b] : (which == 1 ? pos[b] + kNU : neg[b] + kNU);
  H8 v = (node < kNU) ? hU[(long)node * 8 + q] : hI[(long)(node - kNU) * 8 + q];
  float sq = sqrtf((float)max(deg[node], 1));
  float2 f0 = __half22float2(v.h[0]), f1 = __half22float2(v.h[1]);
  float2 f2 = __half22float2(v.h[2]), f3 = __half22float2(v.h[3]);
  float4 r0 = {f0.x * sq, f0.y * sq, f1.x * sq, f1.y * sq};
  float4 r1 = {f2.x * sq, f2.y * sq, f3.x * sq, f3.y * sq};
  long o0 = (long)slot * 16 + q * 2;
  if (add) {
    float4 a0 = out[o0], a1 = out[o0 + 1];
    r0.x += a0.x; r0.y += a0.y; r0.z += a0.z; r0.w += a0.w;
    r1.x += a1.x; r1.y += a1.y; r1.z += a1.z; r1.w += a1.w;
  }
  out[o0] = r0; out[o0 + 1] = r1;
}

// ---------------- layer 3 restricted + /4 + per-row L2 ----------------------
__global__ void layer3_fin(const int* __restrict__ rs, const unsigned short* __restrict__ cols,
                           const float* __restrict__ rsDg,
                           const H8* __restrict__ hU, const H8* __restrict__ hI,
                           const int* __restrict__ users, const int* __restrict__ pos,
                           const int* __restrict__ neg,
                           float4* __restrict__ out, float* __restrict__ l2part) {
  int slot = blockIdx.x * 4 + (threadIdx.x >> 6);
  if (slot >= 3 * kB) return;
  int lane = threadIdx.x & 63, g = lane >> 3, q = lane & 7;
  int which = slot >> 12, b = slot & (kB - 1);
  int node = which == 0 ? users[b] : (which == 1 ? pos[b] + kNU : neg[b] + kNU);
  const H8* src = (node < kNU) ? hI : hU;
  int s = rs[node], e = rs[node + 1];
  __half2 z = __float2half2_rn(0.f);
  __half2 hacc[4] = {z, z, z, z};
  int j = s + g;
  for (; j + 8 < e; j += 16) {
    int c0 = cols[j], c1 = cols[j + 8];
    H8 v0 = src[(long)c0 * 8 + q];
    H8 v1 = src[(long)c1 * 8 + q];
    #pragma unroll
    for (int k = 0; k < 4; ++k)
      hacc[k] = __hadd2(hacc[k], __hadd2(v0.h[k], v1.h[k]));
  }
  if (j < e) {
    int c = cols[j];
    H8 v = src[(long)c * 8 + q];
    #pragma unroll
    for (int k = 0; k < 4; ++k) hacc[k] = __hadd2(hacc[k], v.h[k]);
  }
  float a[8];
  #pragma unroll
  for (int k = 0; k < 4; ++k) {
    float2 f = __half22float2(hacc[k]);
    a[2 * k] = f.x; a[2 * k + 1] = f.y;
  }
  #pragma unroll
  for (int m = 8; m <= 32; m <<= 1) {
    #pragma unroll
    for (int k = 0; k < 8; ++k) a[k] += __shfl_xor(a[k], m, 64);
  }
  float t = 0.f;
  if (g == 0) {
    float sr = rsDg[node];   // y3 = rsDg * sum(in~)
    long o0 = (long)slot * 16 + q * 2;
    float4 a0 = out[o0], a1 = out[o0 + 1];
    float4 r0 = {(a0.x + a[0] * sr) * 0.25f, (a0.y + a[1] * sr) * 0.25f,
                 (a0.z + a[2] * sr) * 0.25f, (a0.w + a[3] * sr) * 0.25f};
    float4 r1 = {(a1.x + a[4] * sr) * 0.25f, (a1.y + a[5] * sr) * 0.25f,
                 (a1.z + a[6] * sr) * 0.25f, (a1.w + a[7] * sr) * 0.25f};
    out[o0] = r0; out[o0 + 1] = r1;
    t = r0.x * r0.x + r0.y * r0.y + r0.z * r0.z + r0.w * r0.w
      + r1.x * r1.x + r1.y * r1.y + r1.z * r1.z + r1.w * r1.w;
  }
  #pragma unroll
  for (int m = 1; m <= 4; m <<= 1) t += __shfl_xor(t, m, 64);
  if (lane == 0) l2part[slot] = t;
}

__global__ void l2_final(const float* __restrict__ l2part, float* __restrict__ outl2) {
  int b = blockIdx.x * blockDim.x + threadIdx.x;
  if (b < kB) outl2[b] = l2part[b] + l2part[kB + b] + l2part[2 * kB + b];
}

extern "C" void kernel_launch(void* const* d_in, const int* in_sizes, int n_in,
                              void* d_out, int out_size, void* d_ws, size_t ws_size,
                              hipStream_t stream) {
  const float* emb  = (const float*)d_in[0];
  const int*   arow = (const int*)d_in[3];
  const int*   users= (const int*)d_in[5];
  const int*   pos  = (const int*)d_in[6];
  const int*   neg  = (const int*)d_in[7];
  const int neA = in_sizes[3];              // 2,000,000
  const int nP  = neA / 2;                  // 1,000,000 pairs
  const int nV  = nP / 4;                   // 250,000 int4
  const int4* u4 = (const int4*)arow;
  const int4* i4 = (const int4*)(arow + nP);

  char* ws = (char*)d_ws;
  int*            degA     = (int*)(ws + 0);            // 400,000
  int*            rowStart = (int*)(ws + 400000);       // 400,004 (pad to 800128)
  float*          rsDg     = (float*)(ws + 800128);     // 400,000
  float*          l2part   = (float*)(ws + 1200128);    // 49,152
  int*            bsum     = (int*)(ws + 1249280);      // 1,024
  unsigned short* colA     = (unsigned short*)(ws + 1250304);  // 4,000,000
  __half*         emb16    = (__half*)(ws + 5250304);   // 12,800,256 -> 18,050,560
  // hist (25,600,000 B) ALIASES the state buffers: dead once scatter_h is done.
  int*            hist     = (int*)(ws + 18050560);
  __half*         hU0      = (__half*)(ws + 18050560);  // 7,680,000
  __half*         hU1      = (__half*)(ws + 25730560);  // 7,680,000
  __half*         hI0      = (__half*)(ws + 33410560);  // 5,120,000
  __half*         hI1      = (__half*)(ws + 38530560);  // 5,120,000 -> end 43,650,560

  float* out = (float*)d_out;
  const int NB = (kN + SCAN_CH - 1) / SCAN_CH;  // 49
  const int RG = (kN + 255) / 256;              // 391

  hist_k<<<NR * NC, 256, 0, stream>>>(u4, i4, nV, hist);
  degsum_k<<<RG, 256, 0, stream>>>(hist, degA, rsDg);
  scan_p1<<<NB, SCAN_T, 0, stream>>>(degA, kN, bsum);
  scan_p2<<<1, 64, 0, stream>>>(bsum, NB);
  scan_p3<<<NB, SCAN_T, 0, stream>>>(degA, kN, neA, bsum, rowStart);
  const int nE16 = 100002 * 16;   // float4 elements in emb
  emb_to_h<<<(nE16 + 255) / 256, 256, 0, stream>>>((const float4*)emb, (H4*)emb16, nE16);
  expand_k<<<RG, 256, 0, stream>>>(hist, rowStart);
  scatter_h<<<NR * NC, 256, 0, stream>>>(u4, i4, nV, hist, colA);

  const int GN = (kN + 31) / 32;   // 3125 blocks, 32 rows each (8 per wave)

  // feature SpMM -> fp16 scaled state y~0 (overwrites hist region; hist dead)
  spmm_feat_all<<<GN, 256, 0, stream>>>(rowStart, colA, (const H8*)emb16, rsDg,
                                        (H8*)hU0, (H8*)hI0);
  acc_gather_h<<<(3 * kB * 8 + 255) / 256, 256, 0, stream>>>((const H8*)hU0, (const H8*)hI0,
      degA, users, pos, neg, (float4*)out, 0);

  // layer 1: (hU0,hI0) -> (hU1,hI1)
  spmm_adj_all<<<GN, 256, 0, stream>>>(rowStart, colA, rsDg, (const H8*)hU0, (const H8*)hI0,
                                       (H8*)hU1, (H8*)hI1);
  acc_gather_h<<<(3 * kB * 8 + 255) / 256, 256, 0, stream>>>((const H8*)hU1, (const H8*)hI1,
      degA, users, pos, neg, (float4*)out, 1);

  // layer 2: (hU1,hI1) -> (hU0,hI0)
  spmm_adj_all<<<GN, 256, 0, stream>>>(rowStart, colA, rsDg, (const H8*)hU1, (const H8*)hI1,
                                       (H8*)hU0, (H8*)hI0);
  acc_gather_h<<<(3 * kB * 8 + 255) / 256, 256, 0, stream>>>((const H8*)hU0, (const H8*)hI0,
      degA, users, pos, neg, (float4*)out, 1);

  // layer 3 restricted + epilogue (reads layer-2 state)
  layer3_fin<<<(3 * kB + 3) / 4, 256, 0, stream>>>(rowStart, colA, rsDg, (const H8*)hU0,
                                                   (const H8*)hI0, users, pos, neg,
                                                   (float4*)out, l2part);
  l2_final<<<(kB + 255) / 256, 256, 0, stream>>>(l2part, out + 3 * kB * 64);
}